// Round 26
// baseline (12286.143 us; speedup 1.0000x reference)
//
// DeepARS4_74010876445305 -- vQ: f32 pipeline, FLOAT32 outputs (the fix)
#include <hip/hip_runtime.h>
#include <hip/hip_bf16.h>

#define BB 32
#define LL 2048
#define DIN 33
#define HH 512
#define NLAYER 4
#define NN 32
#define ML (BB * LL)

__device__ __forceinline__ float ds4q_softplus(float x) {
  return (x > 20.0f) ? x : log1pf(expf(x));
}

// ---- encoder ----
__global__ void ds4q_encoder(const float* __restrict__ x, const float* __restrict__ ew,
                             const float* __restrict__ eb, float* __restrict__ H) {
  __shared__ float xrow[DIN];
  const int row = blockIdx.x;
  const int tid = threadIdx.x;
  if (tid < DIN) xrow[tid] = x[(size_t)row * DIN + tid];
  __syncthreads();
  for (int half = 0; half < 2; ++half) {
    const int j = tid + half * 256;
    float acc = eb[j];
#pragma unroll
    for (int k = 0; k < DIN; ++k) acc = fmaf(xrow[k], ew[(size_t)k * HH + j], acc);
    H[(size_t)row * HH + j] = acc;
  }
}

// ---- S4D diagonal scan (ZOH), one thread per (b,h) ----
__global__ __launch_bounds__(64) void ds4q_ssm(
    const float* __restrict__ Hin, float* __restrict__ Y,
    const float* __restrict__ log_dt, const float* __restrict__ Cpk,
    const float* __restrict__ logAre, const float* __restrict__ Aimag,
    const float* __restrict__ Dvec) {
  const int t = blockIdx.x * 64 + threadIdx.x;
  const int h = t & (HH - 1);
  const int b = t >> 9;

  const float dt = expf(log_dt[h]);
  const float Dh = Dvec[h];

  float wre[NN], wim[NN], cre[NN], cim[NN], sre[NN], sim[NN];
#pragma unroll
  for (int n = 0; n < NN; ++n) {
    const size_t p = (size_t)h * NN + n;
    const float Are = -expf(logAre[p]);
    const float Aim = Aimag[p];
    const float mag = expf(Are * dt);
    const float cwr = mag * cosf(Aim * dt);
    const float cwi = mag * sinf(Aim * dt);
    wre[n] = cwr; wim[n] = cwi;
    const float inv = 1.0f / (Are * Are + Aim * Aim);
    const float qr = ((cwr - 1.0f) * Are + cwi * Aim) * inv;
    const float qi = (cwi * Are - (cwr - 1.0f) * Aim) * inv;
    const float Cr = Cpk[p * 2], Ci = Cpk[p * 2 + 1];
    cre[n] = Cr * qr - Ci * qi;
    cim[n] = Cr * qi + Ci * qr;
    sre[n] = 0.0f; sim[n] = 0.0f;
  }

  const float* uptr = Hin + (size_t)b * LL * HH + h;
  float* yptr = Y + (size_t)b * LL * HH + h;

  for (int l = 0; l < LL; ++l) {
    const float u = uptr[(size_t)l * HH];
    float acc = 0.0f;
#pragma unroll
    for (int n = 0; n < NN; ++n) {
      const float nr = fmaf(wre[n], sre[n], fmaf(-wim[n], sim[n], u));
      const float ni = fmaf(wim[n], sre[n], wre[n] * sim[n]);
      sre[n] = nr; sim[n] = ni;
      acc = fmaf(cre[n], nr, fmaf(-cim[n], ni, acc));
    }
    const float yv = fmaf(2.0f, acc, Dh * u);
    const float gl = 0.5f * yv * (1.0f + erff(yv * 0.70710678118654752f));
    yptr[(size_t)l * HH] = gl;
  }
}

// ---- fused GEMM (both GLU halves) + bias + GLU ----
__global__ __launch_bounds__(256) void ds4q_mlp(
    const float* __restrict__ Y, const float* __restrict__ W,
    const float* __restrict__ bias, float* __restrict__ Z) {
  __shared__ float tA[16][128];
  __shared__ float tWa[16][64];
  __shared__ float tWg[16][64];

  const int tid = threadIdx.x;
  const int m0 = blockIdx.x * 128;
  const int o0 = blockIdx.y * 64;
  const int tx = tid & 15;
  const int ty = tid >> 4;

  float ra[8][4] = {};
  float rg[8][4] = {};

  for (int k0 = 0; k0 < HH; k0 += 16) {
#pragma unroll
    for (int e = 0; e < 8; ++e) {
      const int el = tid * 8 + e;
      tA[el & 15][el >> 4] = Y[(size_t)(m0 + (el >> 4)) * HH + k0 + (el & 15)];
    }
#pragma unroll
    for (int e = 0; e < 4; ++e) {
      const int el = tid * 4 + e;
      tWa[el & 15][el >> 4] = W[(size_t)(o0 + (el >> 4)) * HH + k0 + (el & 15)];
      tWg[el & 15][el >> 4] = W[(size_t)(o0 + 512 + (el >> 4)) * HH + k0 + (el & 15)];
    }
    __syncthreads();

#pragma unroll
    for (int kk = 0; kk < 16; ++kk) {
      float av[8], ba[4], bg[4];
#pragma unroll
      for (int i = 0; i < 8; ++i) av[i] = tA[kk][ty * 8 + i];
#pragma unroll
      for (int j = 0; j < 4; ++j) { ba[j] = tWa[kk][tx * 4 + j]; bg[j] = tWg[kk][tx * 4 + j]; }
#pragma unroll
      for (int i = 0; i < 8; ++i)
#pragma unroll
        for (int j = 0; j < 4; ++j) {
          ra[i][j] = fmaf(av[i], ba[j], ra[i][j]);
          rg[i][j] = fmaf(av[i], bg[j], rg[i][j]);
        }
    }
    __syncthreads();
  }

#pragma unroll
  for (int i = 0; i < 8; ++i)
#pragma unroll
    for (int j = 0; j < 4; ++j) {
      const int m = m0 + ty * 8 + i;
      const int oc = o0 + tx * 4 + j;
      const float a = ra[i][j] + bias[oc];
      const float g = rg[i][j] + bias[512 + oc];
      Z[(size_t)m * HH + oc] = a / (1.0f + expf(-g));
    }
}

// ---- residual + LayerNorm (postnorm) ----
__global__ void ds4q_postnorm(const float* __restrict__ Z, float* __restrict__ H,
                              const float* __restrict__ gw, const float* __restrict__ gb) {
  __shared__ float red1[256];
  __shared__ float red2[256];
  const int row = blockIdx.x;
  const int tid = threadIdx.x;
  const float* zp = Z + (size_t)row * HH;
  float* hp = H + (size_t)row * HH;
  const float a0 = zp[tid] + hp[tid];
  const float a1 = zp[tid + 256] + hp[tid + 256];
  red1[tid] = a0 + a1;
  red2[tid] = fmaf(a0, a0, a1 * a1);
  __syncthreads();
  for (int off = 128; off > 0; off >>= 1) {
    if (tid < off) { red1[tid] += red1[tid + off]; red2[tid] += red2[tid + off]; }
    __syncthreads();
  }
  const float mean = red1[0] * (1.0f / HH);
  const float var = red2[0] * (1.0f / HH) - mean * mean;
  const float rstd = rsqrtf(var + 1e-5f);
  hp[tid] = (a0 - mean) * rstd * gw[tid] + gb[tid];
  hp[tid + 256] = (a1 - mean) * rstd * gw[tid + 256] + gb[tid + 256];
}

// ---- heads: mu/alpha = softplus(h.w + b), stored as FLOAT32 ----
__global__ void ds4q_project(const float* __restrict__ H, const float* __restrict__ mw,
                             const float* __restrict__ mb, const float* __restrict__ aw,
                             const float* __restrict__ ab,
                             float* __restrict__ mu_out, float* __restrict__ al_out) {
  __shared__ float red1[256];
  __shared__ float red2[256];
  const int row = blockIdx.x;
  const int tid = threadIdx.x;
  const float* hp = H + (size_t)row * HH;
  const float v0 = hp[tid], v1 = hp[tid + 256];
  red1[tid] = fmaf(v0, mw[tid], v1 * mw[tid + 256]);
  red2[tid] = fmaf(v0, aw[tid], v1 * aw[tid + 256]);
  __syncthreads();
  for (int off = 128; off > 0; off >>= 1) {
    if (tid < off) { red1[tid] += red1[tid + off]; red2[tid] += red2[tid + off]; }
    __syncthreads();
  }
  if (tid == 0) {
    mu_out[row] = ds4q_softplus(red1[0] + mb[0]);
    al_out[row] = ds4q_softplus(red2[0] + ab[0]);
  }
}

extern "C" void kernel_launch(void* const* d_in, const int* in_sizes, int n_in,
                              void* d_out, int out_size, void* d_ws, size_t ws_size,
                              hipStream_t stream) {
  const float* x      = (const float*)d_in[0];
  const float* enc_w  = (const float*)d_in[1];
  const float* enc_b  = (const float*)d_in[2];
  const float* log_dt = (const float*)d_in[3];
  const float* Cpk    = (const float*)d_in[4];
  const float* logAre = (const float*)d_in[5];
  const float* Aimag  = (const float*)d_in[6];
  const float* Dvec   = (const float*)d_in[7];
  const float* out_w  = (const float*)d_in[8];
  const float* out_b  = (const float*)d_in[9];
  const float* norm_w = (const float*)d_in[10];
  const float* norm_b = (const float*)d_in[11];
  const float* mu_w   = (const float*)d_in[12];
  const float* mu_b   = (const float*)d_in[13];
  const float* al_w   = (const float*)d_in[14];
  const float* al_b   = (const float*)d_in[15];

  const size_t seqBytes = (size_t)LL * HH * 4;
  int Bc = BB;
  while (Bc > 1 && 3 * seqBytes * (size_t)Bc > ws_size) Bc >>= 1;

  float* Hbuf = (float*)d_ws;
  float* Ybuf = Hbuf + (size_t)Bc * LL * HH;
  float* Zbuf = Ybuf + (size_t)Bc * LL * HH;

  // FLOAT32 outputs: mu = d_out[0:ML], alpha = d_out[ML:2*ML]
  float* mu_out = (float*)d_out;
  float* al_out = mu_out + (size_t)ML;

  for (int cb = 0; cb < BB; cb += Bc) {
    const int rows = Bc * LL;
    ds4q_encoder<<<rows, 256, 0, stream>>>(x + (size_t)cb * LL * DIN, enc_w, enc_b, Hbuf);

    for (int layer = 0; layer < NLAYER; ++layer) {
      ds4q_ssm<<<(Bc * HH) / 64, 64, 0, stream>>>(
          Hbuf, Ybuf,
          log_dt + (size_t)layer * HH, Cpk + (size_t)layer * HH * NN * 2,
          logAre + (size_t)layer * HH * NN, Aimag + (size_t)layer * HH * NN,
          Dvec + (size_t)layer * HH);
      dim3 grid(rows / 128, 8, 1);
      ds4q_mlp<<<grid, 256, 0, stream>>>(
          Ybuf, out_w + (size_t)layer * 1024 * 512, out_b + (size_t)layer * 1024, Zbuf);
      ds4q_postnorm<<<rows, 256, 0, stream>>>(
          Zbuf, Hbuf, norm_w + (size_t)layer * HH, norm_b + (size_t)layer * HH);
    }

    ds4q_project<<<rows, 256, 0, stream>>>(
        Hbuf, mu_w, mu_b, al_w, al_b,
        mu_out + (size_t)cb * LL, al_out + (size_t)cb * LL);
  }
}

// Round 27
// 6146.811 us; speedup vs baseline: 1.9988x; 1.9988x over previous
//
// DeepARS4_74010876445305 -- vR: chunk-parallel scan (16x parallelism), f32 outputs
#include <hip/hip_runtime.h>
#include <hip/hip_bf16.h>

#define BB 32
#define LL 2048
#define DIN 33
#define HH 512
#define NLAYER 4
#define NN 32
#define ML (BB * LL)
#define CT 128   // scan chunk length
#define NC 16    // chunks per sequence (CT*NC == LL)

__device__ __forceinline__ float ds4r_softplus(float x) {
  return (x > 20.0f) ? x : log1pf(expf(x));
}

// ---- encoder ----
__global__ void ds4r_encoder(const float* __restrict__ x, const float* __restrict__ ew,
                             const float* __restrict__ eb, float* __restrict__ H) {
  __shared__ float xrow[DIN];
  const int row = blockIdx.x;
  const int tid = threadIdx.x;
  if (tid < DIN) xrow[tid] = x[(size_t)row * DIN + tid];
  __syncthreads();
  for (int half = 0; half < 2; ++half) {
    const int j = tid + half * 256;
    float acc = eb[j];
#pragma unroll
    for (int k = 0; k < DIN; ++k) acc = fmaf(xrow[k], ew[(size_t)k * HH + j], acc);
    H[(size_t)row * HH + j] = acc;
  }
}

// ---- scan pass 1: per (b,chunk,h) local scan, record end-state E[bh][c][n] ----
__global__ __launch_bounds__(64) void ds4r_ssm_p1(
    const float* __restrict__ Hin, float* __restrict__ E,
    const float* __restrict__ log_dt, const float* __restrict__ logAre,
    const float* __restrict__ Aimag) {
  const int blk = blockIdx.x;
  const int hblk = blk & 7;
  const int c = (blk >> 3) & (NC - 1);
  const int b = blk >> 7;
  const int h = hblk * 64 + threadIdx.x;

  const float dt = expf(log_dt[h]);
  float wre[NN], wim[NN], sre[NN], sim[NN];
#pragma unroll
  for (int n = 0; n < NN; ++n) {
    const size_t p = (size_t)h * NN + n;
    const float Are = -expf(logAre[p]);
    const float Aim = Aimag[p];
    const float mag = expf(Are * dt);
    wre[n] = mag * cosf(Aim * dt);
    wim[n] = mag * sinf(Aim * dt);
    sre[n] = 0.0f; sim[n] = 0.0f;
  }

  const float* uptr = Hin + ((size_t)b * LL + (size_t)c * CT) * HH + h;
  float unext = uptr[0];
  for (int i = 0; i < CT; ++i) {
    const float u = unext;
    if (i + 1 < CT) unext = uptr[(size_t)(i + 1) * HH];
#pragma unroll
    for (int n = 0; n < NN; ++n) {
      const float nr = fmaf(wre[n], sre[n], fmaf(-wim[n], sim[n], u));
      const float ni = fmaf(wim[n], sre[n], wre[n] * sim[n]);
      sre[n] = nr; sim[n] = ni;
    }
  }
  float* ep = E + (((size_t)(b * 512 + h) * NC + c) * NN) * 2;
#pragma unroll
  for (int n = 0; n < NN; ++n) { ep[2 * n] = sre[n]; ep[2 * n + 1] = sim[n]; }
}

// ---- scan combine: exclusive prefix over chunks per (bh, n): S_c = w^CT S_{c-1} + E_{c-1} ----
__global__ void ds4r_ssm_comb(float* __restrict__ E, const float* __restrict__ log_dt,
                              const float* __restrict__ logAre, const float* __restrict__ Aimag) {
  const int gid = blockIdx.x * 256 + threadIdx.x;   // bh*32 + n
  const int n = gid & 31;
  const int bh = gid >> 5;
  const int h = bh & 511;
  const float dt = expf(log_dt[h]);
  const size_t p = (size_t)h * NN + n;
  const float Are = -expf(logAre[p]);
  const float Aim = Aimag[p];
  const float magT = expf((float)CT * Are * dt);
  const float angT = (float)CT * Aim * dt;
  const float wTr = magT * cosf(angT);
  const float wTi = magT * sinf(angT);
  float* ep = E + ((size_t)bh * NC * NN + n) * 2;
  float Sr = 0.0f, Si = 0.0f;
  for (int c = 0; c < NC; ++c) {
    const float Er = ep[(size_t)c * NN * 2];
    const float Ei = ep[(size_t)c * NN * 2 + 1];
    ep[(size_t)c * NN * 2] = Sr;
    ep[(size_t)c * NN * 2 + 1] = Si;
    const float nSr = fmaf(wTr, Sr, fmaf(-wTi, Si, Er));
    const float nSi = fmaf(wTi, Sr, fmaf(wTr, Si, Ei));
    Sr = nSr; Si = nSi;
  }
}

// ---- scan pass 2: seeded local scan + y + D-skip + gelu -> Y ----
__global__ __launch_bounds__(64) void ds4r_ssm_p2(
    const float* __restrict__ Hin, float* __restrict__ Y, const float* __restrict__ E,
    const float* __restrict__ log_dt, const float* __restrict__ Cpk,
    const float* __restrict__ logAre, const float* __restrict__ Aimag,
    const float* __restrict__ Dvec) {
  const int blk = blockIdx.x;
  const int hblk = blk & 7;
  const int c = (blk >> 3) & (NC - 1);
  const int b = blk >> 7;
  const int h = hblk * 64 + threadIdx.x;

  const float dt = expf(log_dt[h]);
  const float Dh = Dvec[h];

  float wre[NN], wim[NN], cre[NN], cim[NN], sre[NN], sim[NN];
  const float* ep = E + (((size_t)(b * 512 + h) * NC + c) * NN) * 2;
#pragma unroll
  for (int n = 0; n < NN; ++n) {
    const size_t p = (size_t)h * NN + n;
    const float Are = -expf(logAre[p]);
    const float Aim = Aimag[p];
    const float mag = expf(Are * dt);
    const float cwr = mag * cosf(Aim * dt);
    const float cwi = mag * sinf(Aim * dt);
    wre[n] = cwr; wim[n] = cwi;
    const float inv = 1.0f / (Are * Are + Aim * Aim);
    const float qr = ((cwr - 1.0f) * Are + cwi * Aim) * inv;
    const float qi = (cwi * Are - (cwr - 1.0f) * Aim) * inv;
    const float Cr = Cpk[p * 2], Ci = Cpk[p * 2 + 1];
    cre[n] = Cr * qr - Ci * qi;
    cim[n] = Cr * qi + Ci * qr;
    sre[n] = ep[2 * n];
    sim[n] = ep[2 * n + 1];
  }

  const float* uptr = Hin + ((size_t)b * LL + (size_t)c * CT) * HH + h;
  float* yptr = Y + ((size_t)b * LL + (size_t)c * CT) * HH + h;

  float unext = uptr[0];
  for (int i = 0; i < CT; ++i) {
    const float u = unext;
    if (i + 1 < CT) unext = uptr[(size_t)(i + 1) * HH];
    float acc = 0.0f;
#pragma unroll
    for (int n = 0; n < NN; ++n) {
      const float nr = fmaf(wre[n], sre[n], fmaf(-wim[n], sim[n], u));
      const float ni = fmaf(wim[n], sre[n], wre[n] * sim[n]);
      sre[n] = nr; sim[n] = ni;
      acc = fmaf(cre[n], nr, fmaf(-cim[n], ni, acc));
    }
    const float yv = fmaf(2.0f, acc, Dh * u);
    const float gl = 0.5f * yv * (1.0f + erff(yv * 0.70710678118654752f));
    yptr[(size_t)i * HH] = gl;
  }
}

// ---- fused GEMM (both GLU halves) + bias + GLU ----
__global__ __launch_bounds__(256) void ds4r_mlp(
    const float* __restrict__ Y, const float* __restrict__ W,
    const float* __restrict__ bias, float* __restrict__ Z) {
  __shared__ float tA[16][128];
  __shared__ float tWa[16][64];
  __shared__ float tWg[16][64];

  const int tid = threadIdx.x;
  const int m0 = blockIdx.x * 128;
  const int o0 = blockIdx.y * 64;
  const int tx = tid & 15;
  const int ty = tid >> 4;

  float ra[8][4] = {};
  float rg[8][4] = {};

  for (int k0 = 0; k0 < HH; k0 += 16) {
#pragma unroll
    for (int e = 0; e < 8; ++e) {
      const int el = tid * 8 + e;
      tA[el & 15][el >> 4] = Y[(size_t)(m0 + (el >> 4)) * HH + k0 + (el & 15)];
    }
#pragma unroll
    for (int e = 0; e < 4; ++e) {
      const int el = tid * 4 + e;
      tWa[el & 15][el >> 4] = W[(size_t)(o0 + (el >> 4)) * HH + k0 + (el & 15)];
      tWg[el & 15][el >> 4] = W[(size_t)(o0 + 512 + (el >> 4)) * HH + k0 + (el & 15)];
    }
    __syncthreads();

#pragma unroll
    for (int kk = 0; kk < 16; ++kk) {
      float av[8], ba[4], bg[4];
#pragma unroll
      for (int i = 0; i < 8; ++i) av[i] = tA[kk][ty * 8 + i];
#pragma unroll
      for (int j = 0; j < 4; ++j) { ba[j] = tWa[kk][tx * 4 + j]; bg[j] = tWg[kk][tx * 4 + j]; }
#pragma unroll
      for (int i = 0; i < 8; ++i)
#pragma unroll
        for (int j = 0; j < 4; ++j) {
          ra[i][j] = fmaf(av[i], ba[j], ra[i][j]);
          rg[i][j] = fmaf(av[i], bg[j], rg[i][j]);
        }
    }
    __syncthreads();
  }

#pragma unroll
  for (int i = 0; i < 8; ++i)
#pragma unroll
    for (int j = 0; j < 4; ++j) {
      const int m = m0 + ty * 8 + i;
      const int oc = o0 + tx * 4 + j;
      const float a = ra[i][j] + bias[oc];
      const float g = rg[i][j] + bias[512 + oc];
      Z[(size_t)m * HH + oc] = a / (1.0f + expf(-g));
    }
}

// ---- residual + LayerNorm (postnorm) ----
__global__ void ds4r_postnorm(const float* __restrict__ Z, float* __restrict__ H,
                              const float* __restrict__ gw, const float* __restrict__ gb) {
  __shared__ float red1[256];
  __shared__ float red2[256];
  const int row = blockIdx.x;
  const int tid = threadIdx.x;
  const float* zp = Z + (size_t)row * HH;
  float* hp = H + (size_t)row * HH;
  const float a0 = zp[tid] + hp[tid];
  const float a1 = zp[tid + 256] + hp[tid + 256];
  red1[tid] = a0 + a1;
  red2[tid] = fmaf(a0, a0, a1 * a1);
  __syncthreads();
  for (int off = 128; off > 0; off >>= 1) {
    if (tid < off) { red1[tid] += red1[tid + off]; red2[tid] += red2[tid + off]; }
    __syncthreads();
  }
  const float mean = red1[0] * (1.0f / HH);
  const float var = red2[0] * (1.0f / HH) - mean * mean;
  const float rstd = rsqrtf(var + 1e-5f);
  hp[tid] = (a0 - mean) * rstd * gw[tid] + gb[tid];
  hp[tid + 256] = (a1 - mean) * rstd * gw[tid + 256] + gb[tid + 256];
}

// ---- heads: mu/alpha = softplus(h.w + b), FLOAT32 out ----
__global__ void ds4r_project(const float* __restrict__ H, const float* __restrict__ mw,
                             const float* __restrict__ mb, const float* __restrict__ aw,
                             const float* __restrict__ ab,
                             float* __restrict__ mu_out, float* __restrict__ al_out) {
  __shared__ float red1[256];
  __shared__ float red2[256];
  const int row = blockIdx.x;
  const int tid = threadIdx.x;
  const float* hp = H + (size_t)row * HH;
  const float v0 = hp[tid], v1 = hp[tid + 256];
  red1[tid] = fmaf(v0, mw[tid], v1 * mw[tid + 256]);
  red2[tid] = fmaf(v0, aw[tid], v1 * aw[tid + 256]);
  __syncthreads();
  for (int off = 128; off > 0; off >>= 1) {
    if (tid < off) { red1[tid] += red1[tid + off]; red2[tid] += red2[tid + off]; }
    __syncthreads();
  }
  if (tid == 0) {
    mu_out[row] = ds4r_softplus(red1[0] + mb[0]);
    al_out[row] = ds4r_softplus(red2[0] + ab[0]);
  }
}

extern "C" void kernel_launch(void* const* d_in, const int* in_sizes, int n_in,
                              void* d_out, int out_size, void* d_ws, size_t ws_size,
                              hipStream_t stream) {
  const float* x      = (const float*)d_in[0];
  const float* enc_w  = (const float*)d_in[1];
  const float* enc_b  = (const float*)d_in[2];
  const float* log_dt = (const float*)d_in[3];
  const float* Cpk    = (const float*)d_in[4];
  const float* logAre = (const float*)d_in[5];
  const float* Aimag  = (const float*)d_in[6];
  const float* Dvec   = (const float*)d_in[7];
  const float* out_w  = (const float*)d_in[8];
  const float* out_b  = (const float*)d_in[9];
  const float* norm_w = (const float*)d_in[10];
  const float* norm_b = (const float*)d_in[11];
  const float* mu_w   = (const float*)d_in[12];
  const float* mu_b   = (const float*)d_in[13];
  const float* al_w   = (const float*)d_in[14];
  const float* al_b   = (const float*)d_in[15];

  // per-seq bytes: 3 f32 buffers (H,Y,Z) + E states (512*NC*NN*2 f32 = 2 MiB)
  const size_t seqBytes = (size_t)LL * HH * 4;
  const size_t eSeqBytes = (size_t)512 * NC * NN * 2 * 4;
  int Bc = BB;
  while (Bc > 1 && (3 * seqBytes + eSeqBytes) * (size_t)Bc > ws_size) Bc >>= 1;

  float* Hbuf = (float*)d_ws;
  float* Ybuf = Hbuf + (size_t)Bc * LL * HH;
  float* Zbuf = Ybuf + (size_t)Bc * LL * HH;
  float* Ebuf = Zbuf + (size_t)Bc * LL * HH;

  float* mu_out = (float*)d_out;
  float* al_out = mu_out + (size_t)ML;

  for (int cb = 0; cb < BB; cb += Bc) {
    const int rows = Bc * LL;
    ds4r_encoder<<<rows, 256, 0, stream>>>(x + (size_t)cb * LL * DIN, enc_w, enc_b, Hbuf);

    for (int layer = 0; layer < NLAYER; ++layer) {
      const float* ldt = log_dt + (size_t)layer * HH;
      const float* lar = logAre + (size_t)layer * HH * NN;
      const float* aim = Aimag + (size_t)layer * HH * NN;

      ds4r_ssm_p1<<<Bc * NC * 8, 64, 0, stream>>>(Hbuf, Ebuf, ldt, lar, aim);
      ds4r_ssm_comb<<<(Bc * 512 * 32) / 256, 256, 0, stream>>>(Ebuf, ldt, lar, aim);
      ds4r_ssm_p2<<<Bc * NC * 8, 64, 0, stream>>>(
          Hbuf, Ybuf, Ebuf, ldt, Cpk + (size_t)layer * HH * NN * 2, lar, aim,
          Dvec + (size_t)layer * HH);

      dim3 grid(rows / 128, 8, 1);
      ds4r_mlp<<<grid, 256, 0, stream>>>(
          Ybuf, out_w + (size_t)layer * 1024 * 512, out_b + (size_t)layer * 1024, Zbuf);
      ds4r_postnorm<<<rows, 256, 0, stream>>>(
          Zbuf, Hbuf, norm_w + (size_t)layer * HH, norm_b + (size_t)layer * HH);
    }

    ds4r_project<<<rows, 256, 0, stream>>>(
        Hbuf, mu_w, mu_b, al_w, al_b,
        mu_out + (size_t)cb * LL, al_out + (size_t)cb * LL);
  }
}

// Round 28
// 4541.744 us; speedup vs baseline: 2.7052x; 1.3534x over previous
//
// DeepARS4_74010876445305 -- vS: MFMA bf16 mlp + NC=32 chunk scan, f32 outputs
#include <hip/hip_runtime.h>
#include <hip/hip_bf16.h>

#define BB 32
#define LL 2048
#define DIN 33
#define HH 512
#define NLAYER 4
#define NN 32
#define ML (BB * LL)
#define CT 64    // scan chunk length
#define NC 32    // chunks per sequence (CT*NC == LL)

typedef __attribute__((ext_vector_type(8))) short short8;
typedef __attribute__((ext_vector_type(4))) float f32x4;

__device__ __forceinline__ float ds4s_softplus(float x) {
  return (x > 20.0f) ? x : log1pf(expf(x));
}

// ---- weights f32 -> bf16 (once) ----
__global__ void ds4s_wconv(const float* __restrict__ w, __hip_bfloat16* __restrict__ wb, int n) {
  int i = blockIdx.x * 256 + threadIdx.x;
  if (i < n) wb[i] = __float2bfloat16(w[i]);
}

// ---- encoder ----
__global__ void ds4s_encoder(const float* __restrict__ x, const float* __restrict__ ew,
                             const float* __restrict__ eb, float* __restrict__ H) {
  __shared__ float xrow[DIN];
  const int row = blockIdx.x;
  const int tid = threadIdx.x;
  if (tid < DIN) xrow[tid] = x[(size_t)row * DIN + tid];
  __syncthreads();
  for (int half = 0; half < 2; ++half) {
    const int j = tid + half * 256;
    float acc = eb[j];
#pragma unroll
    for (int k = 0; k < DIN; ++k) acc = fmaf(xrow[k], ew[(size_t)k * HH + j], acc);
    H[(size_t)row * HH + j] = acc;
  }
}

// ---- scan pass 1: local scan per (b,c,h), record end-state ----
__global__ __launch_bounds__(64) void ds4s_ssm_p1(
    const float* __restrict__ Hin, float* __restrict__ E,
    const float* __restrict__ log_dt, const float* __restrict__ logAre,
    const float* __restrict__ Aimag) {
  const int blk = blockIdx.x;
  const int hblk = blk & 7;
  const int c = (blk >> 3) & (NC - 1);
  const int b = blk >> 8;
  const int h = hblk * 64 + threadIdx.x;

  const float dt = expf(log_dt[h]);
  float wre[NN], wim[NN], sre[NN], sim[NN];
#pragma unroll
  for (int n = 0; n < NN; ++n) {
    const size_t p = (size_t)h * NN + n;
    const float Are = -expf(logAre[p]);
    const float Aim = Aimag[p];
    const float mag = expf(Are * dt);
    wre[n] = mag * cosf(Aim * dt);
    wim[n] = mag * sinf(Aim * dt);
    sre[n] = 0.0f; sim[n] = 0.0f;
  }

  const float* uptr = Hin + ((size_t)b * LL + (size_t)c * CT) * HH + h;
  float unext = uptr[0];
  for (int i = 0; i < CT; ++i) {
    const float u = unext;
    if (i + 1 < CT) unext = uptr[(size_t)(i + 1) * HH];
#pragma unroll
    for (int n = 0; n < NN; ++n) {
      const float nr = fmaf(wre[n], sre[n], fmaf(-wim[n], sim[n], u));
      const float ni = fmaf(wim[n], sre[n], wre[n] * sim[n]);
      sre[n] = nr; sim[n] = ni;
    }
  }
  float* ep = E + (((size_t)(b * 512 + h) * NC + c) * NN) * 2;
#pragma unroll
  for (int n = 0; n < NN; ++n) { ep[2 * n] = sre[n]; ep[2 * n + 1] = sim[n]; }
}

// ---- scan combine: exclusive prefix over chunks ----
__global__ void ds4s_ssm_comb(float* __restrict__ E, const float* __restrict__ log_dt,
                              const float* __restrict__ logAre, const float* __restrict__ Aimag) {
  const int gid = blockIdx.x * 256 + threadIdx.x;   // bh*32 + n
  const int n = gid & 31;
  const int bh = gid >> 5;
  const int h = bh & 511;
  const float dt = expf(log_dt[h]);
  const size_t p = (size_t)h * NN + n;
  const float Are = -expf(logAre[p]);
  const float Aim = Aimag[p];
  const float magT = expf((float)CT * Are * dt);
  const float angT = (float)CT * Aim * dt;
  const float wTr = magT * cosf(angT);
  const float wTi = magT * sinf(angT);
  float* ep = E + ((size_t)bh * NC * NN + n) * 2;
  float Sr = 0.0f, Si = 0.0f;
  for (int c = 0; c < NC; ++c) {
    const float Er = ep[(size_t)c * NN * 2];
    const float Ei = ep[(size_t)c * NN * 2 + 1];
    ep[(size_t)c * NN * 2] = Sr;
    ep[(size_t)c * NN * 2 + 1] = Si;
    const float nSr = fmaf(wTr, Sr, fmaf(-wTi, Si, Er));
    const float nSi = fmaf(wTi, Sr, fmaf(wTr, Si, Ei));
    Sr = nSr; Si = nSi;
  }
}

// ---- scan pass 2: seeded scan + D skip + gelu -> Y (bf16) ----
__global__ __launch_bounds__(64) void ds4s_ssm_p2(
    const float* __restrict__ Hin, __hip_bfloat16* __restrict__ Y, const float* __restrict__ E,
    const float* __restrict__ log_dt, const float* __restrict__ Cpk,
    const float* __restrict__ logAre, const float* __restrict__ Aimag,
    const float* __restrict__ Dvec) {
  const int blk = blockIdx.x;
  const int hblk = blk & 7;
  const int c = (blk >> 3) & (NC - 1);
  const int b = blk >> 8;
  const int h = hblk * 64 + threadIdx.x;

  const float dt = expf(log_dt[h]);
  const float Dh = Dvec[h];

  float wre[NN], wim[NN], cre[NN], cim[NN], sre[NN], sim[NN];
  const float* ep = E + (((size_t)(b * 512 + h) * NC + c) * NN) * 2;
#pragma unroll
  for (int n = 0; n < NN; ++n) {
    const size_t p = (size_t)h * NN + n;
    const float Are = -expf(logAre[p]);
    const float Aim = Aimag[p];
    const float mag = expf(Are * dt);
    const float cwr = mag * cosf(Aim * dt);
    const float cwi = mag * sinf(Aim * dt);
    wre[n] = cwr; wim[n] = cwi;
    const float inv = 1.0f / (Are * Are + Aim * Aim);
    const float qr = ((cwr - 1.0f) * Are + cwi * Aim) * inv;
    const float qi = (cwi * Are - (cwr - 1.0f) * Aim) * inv;
    const float Cr = Cpk[p * 2], Ci = Cpk[p * 2 + 1];
    cre[n] = Cr * qr - Ci * qi;
    cim[n] = Cr * qi + Ci * qr;
    sre[n] = ep[2 * n];
    sim[n] = ep[2 * n + 1];
  }

  const float* uptr = Hin + ((size_t)b * LL + (size_t)c * CT) * HH + h;
  __hip_bfloat16* yptr = Y + ((size_t)b * LL + (size_t)c * CT) * HH + h;

  float unext = uptr[0];
  for (int i = 0; i < CT; ++i) {
    const float u = unext;
    if (i + 1 < CT) unext = uptr[(size_t)(i + 1) * HH];
    float acc = 0.0f;
#pragma unroll
    for (int n = 0; n < NN; ++n) {
      const float nr = fmaf(wre[n], sre[n], fmaf(-wim[n], sim[n], u));
      const float ni = fmaf(wim[n], sre[n], wre[n] * sim[n]);
      sre[n] = nr; sim[n] = ni;
      acc = fmaf(cre[n], nr, fmaf(-cim[n], ni, acc));
    }
    const float yv = fmaf(2.0f, acc, Dh * u);
    const float gl = 0.5f * yv * (1.0f + erff(yv * 0.70710678118654752f));
    yptr[(size_t)i * HH] = __float2bfloat16(gl);
  }
}

// ---- MFMA bf16 GEMM + bias + GLU -> Z f32 (structure HW-validated in R2) ----
__global__ __launch_bounds__(256) void ds4s_mlp(
    const __hip_bfloat16* __restrict__ A,    // (M, 512) bf16
    const __hip_bfloat16* __restrict__ W,    // (1024, 512) bf16
    const float* __restrict__ bias,          // (1024)
    float* __restrict__ Z) {                 // (M, 512) f32
  __shared__ __align__(16) unsigned short sA[128 * 32];
  __shared__ __align__(16) unsigned short sW0[128 * 32];
  __shared__ __align__(16) unsigned short sW1[128 * 32];

  const int tid = threadIdx.x;
  const int m0 = blockIdx.x * 128;
  const int o0 = blockIdx.y * 128;     // 0,128,256,384
  const int lane = tid & 63, wid = tid >> 6;
  const int mw = (wid >> 1) * 64, nw = (wid & 1) * 64;
  const int l15 = lane & 15, ko = lane >> 4;

  const unsigned short* Aus = (const unsigned short*)A;
  const unsigned short* Wus = (const unsigned short*)W;

  f32x4 acc[2][4][4] = {};

  for (int kt = 0; kt < 16; ++kt) {
#pragma unroll
    for (int r = 0; r < 2; ++r) {
      const int cidx = tid + r * 256;           // 0..511 chunks of 16B
      const int row = cidx >> 2, kb = cidx & 3;
      const int ldso = row * 32 + kb * 8;
      const int gk = kt * 32 + kb * 8;
      *(uint4*)&sA[ldso]  = *(const uint4*)&Aus[(size_t)(m0 + row) * HH + gk];
      *(uint4*)&sW0[ldso] = *(const uint4*)&Wus[(size_t)(o0 + row) * HH + gk];
      *(uint4*)&sW1[ldso] = *(const uint4*)&Wus[(size_t)(o0 + 512 + row) * HH + gk];
    }
    __syncthreads();

    short8 af[4], wf0[4], wf1[4];
#pragma unroll
    for (int mi = 0; mi < 4; ++mi)
      af[mi] = *(const short8*)&sA[(mw + mi * 16 + l15) * 32 + ko * 8];
#pragma unroll
    for (int ni = 0; ni < 4; ++ni) {
      wf0[ni] = *(const short8*)&sW0[(nw + ni * 16 + l15) * 32 + ko * 8];
      wf1[ni] = *(const short8*)&sW1[(nw + ni * 16 + l15) * 32 + ko * 8];
    }
#pragma unroll
    for (int mi = 0; mi < 4; ++mi)
#pragma unroll
      for (int ni = 0; ni < 4; ++ni) {
        acc[0][mi][ni] = __builtin_amdgcn_mfma_f32_16x16x32_bf16(af[mi], wf0[ni], acc[0][mi][ni], 0, 0, 0);
        acc[1][mi][ni] = __builtin_amdgcn_mfma_f32_16x16x32_bf16(af[mi], wf1[ni], acc[1][mi][ni], 0, 0, 0);
      }
    __syncthreads();
  }

#pragma unroll
  for (int mi = 0; mi < 4; ++mi)
#pragma unroll
    for (int ni = 0; ni < 4; ++ni)
#pragma unroll
      for (int r = 0; r < 4; ++r) {
        const int m = m0 + mw + mi * 16 + ko * 4 + r;
        const int oc = nw + ni * 16 + l15;
        const float a = acc[0][mi][ni][r] + bias[o0 + oc];
        const float g = acc[1][mi][ni][r] + bias[o0 + 512 + oc];
        Z[(size_t)m * HH + o0 + oc] = a / (1.0f + expf(-g));
      }
}

// ---- residual + LayerNorm (postnorm) ----
__global__ void ds4s_postnorm(const float* __restrict__ Z, float* __restrict__ H,
                              const float* __restrict__ gw, const float* __restrict__ gb) {
  __shared__ float red1[256];
  __shared__ float red2[256];
  const int row = blockIdx.x;
  const int tid = threadIdx.x;
  const float* zp = Z + (size_t)row * HH;
  float* hp = H + (size_t)row * HH;
  const float a0 = zp[tid] + hp[tid];
  const float a1 = zp[tid + 256] + hp[tid + 256];
  red1[tid] = a0 + a1;
  red2[tid] = fmaf(a0, a0, a1 * a1);
  __syncthreads();
  for (int off = 128; off > 0; off >>= 1) {
    if (tid < off) { red1[tid] += red1[tid + off]; red2[tid] += red2[tid + off]; }
    __syncthreads();
  }
  const float mean = red1[0] * (1.0f / HH);
  const float var = red2[0] * (1.0f / HH) - mean * mean;
  const float rstd = rsqrtf(var + 1e-5f);
  hp[tid] = (a0 - mean) * rstd * gw[tid] + gb[tid];
  hp[tid + 256] = (a1 - mean) * rstd * gw[tid + 256] + gb[tid + 256];
}

// ---- heads ----
__global__ void ds4s_project(const float* __restrict__ H, const float* __restrict__ mw,
                             const float* __restrict__ mb, const float* __restrict__ aw,
                             const float* __restrict__ ab,
                             float* __restrict__ mu_out, float* __restrict__ al_out) {
  __shared__ float red1[256];
  __shared__ float red2[256];
  const int row = blockIdx.x;
  const int tid = threadIdx.x;
  const float* hp = H + (size_t)row * HH;
  const float v0 = hp[tid], v1 = hp[tid + 256];
  red1[tid] = fmaf(v0, mw[tid], v1 * mw[tid + 256]);
  red2[tid] = fmaf(v0, aw[tid], v1 * aw[tid + 256]);
  __syncthreads();
  for (int off = 128; off > 0; off >>= 1) {
    if (tid < off) { red1[tid] += red1[tid + off]; red2[tid] += red2[tid + off]; }
    __syncthreads();
  }
  if (tid == 0) {
    mu_out[row] = ds4s_softplus(red1[0] + mb[0]);
    al_out[row] = ds4s_softplus(red2[0] + ab[0]);
  }
}

extern "C" void kernel_launch(void* const* d_in, const int* in_sizes, int n_in,
                              void* d_out, int out_size, void* d_ws, size_t ws_size,
                              hipStream_t stream) {
  const float* x      = (const float*)d_in[0];
  const float* enc_w  = (const float*)d_in[1];
  const float* enc_b  = (const float*)d_in[2];
  const float* log_dt = (const float*)d_in[3];
  const float* Cpk    = (const float*)d_in[4];
  const float* logAre = (const float*)d_in[5];
  const float* Aimag  = (const float*)d_in[6];
  const float* Dvec   = (const float*)d_in[7];
  const float* out_w  = (const float*)d_in[8];
  const float* out_b  = (const float*)d_in[9];
  const float* norm_w = (const float*)d_in[10];
  const float* norm_b = (const float*)d_in[11];
  const float* mu_w   = (const float*)d_in[12];
  const float* mu_b   = (const float*)d_in[13];
  const float* al_w   = (const float*)d_in[14];
  const float* al_b   = (const float*)d_in[15];

  // workspace: Wbf(4MiB) + per-seq: H f32(4Mi) + Y bf16(2Mi) + Z f32(4Mi) + E(4Mi) = 14MiB/seq
  const size_t WB = (size_t)NLAYER * 1024 * 512 * 2;
  const size_t seqH = (size_t)LL * HH * 4;
  const size_t seqY = (size_t)LL * HH * 2;
  const size_t seqE = (size_t)512 * NC * NN * 2 * 4;
  int Bc = BB;
  while (Bc > 1 && WB + (2 * seqH + seqY + seqE) * (size_t)Bc > ws_size) Bc >>= 1;

  char* ws = (char*)d_ws;
  __hip_bfloat16* Wbf = (__hip_bfloat16*)ws;
  float* Hbuf = (float*)(ws + WB);
  float* Zbuf = Hbuf + (size_t)Bc * LL * HH;
  __hip_bfloat16* Ybf = (__hip_bfloat16*)(Zbuf + (size_t)Bc * LL * HH);
  float* Ebuf = (float*)((char*)Ybf + (size_t)Bc * seqY);

  float* mu_out = (float*)d_out;
  float* al_out = mu_out + (size_t)ML;

  ds4s_wconv<<<(NLAYER * 1024 * 512 + 255) / 256, 256, 0, stream>>>(
      out_w, Wbf, NLAYER * 1024 * 512);

  for (int cb = 0; cb < BB; cb += Bc) {
    const int rows = Bc * LL;
    ds4s_encoder<<<rows, 256, 0, stream>>>(x + (size_t)cb * LL * DIN, enc_w, enc_b, Hbuf);

    for (int layer = 0; layer < NLAYER; ++layer) {
      const float* ldt = log_dt + (size_t)layer * HH;
      const float* lar = logAre + (size_t)layer * HH * NN;
      const float* aim = Aimag + (size_t)layer * HH * NN;

      ds4s_ssm_p1<<<Bc * NC * 8, 64, 0, stream>>>(Hbuf, Ebuf, ldt, lar, aim);
      ds4s_ssm_comb<<<(Bc * 512 * 32) / 256, 256, 0, stream>>>(Ebuf, ldt, lar, aim);
      ds4s_ssm_p2<<<Bc * NC * 8, 64, 0, stream>>>(
          Hbuf, Ybf, Ebuf, ldt, Cpk + (size_t)layer * HH * NN * 2, lar, aim,
          Dvec + (size_t)layer * HH);

      dim3 grid(rows / 128, 4, 1);
      ds4s_mlp<<<grid, 256, 0, stream>>>(
          Ybf, Wbf + (size_t)layer * 1024 * 512, out_b + (size_t)layer * 1024, Zbuf);
      ds4s_postnorm<<<rows, 256, 0, stream>>>(
          Zbuf, Hbuf, norm_w + (size_t)layer * HH, norm_b + (size_t)layer * HH);
    }

    ds4s_project<<<rows, 256, 0, stream>>>(
        Hbuf, mu_w, mu_b, al_w, al_b,
        mu_out + (size_t)cb * LL, al_out + (size_t)cb * LL);
  }
}

// Round 29
// 3502.149 us; speedup vs baseline: 3.5082x; 1.2968x over previous
//
// DeepARS4_74010876445305 -- vT: mode-parallel scan (8 thr/h, shfl reduce) + MFMA mlp
#include <hip/hip_runtime.h>
#include <hip/hip_bf16.h>

#define BB 32
#define LL 2048
#define DIN 33
#define HH 512
#define NLAYER 4
#define NN 32
#define ML (BB * LL)
#define CT 64    // scan chunk length
#define NC 32    // chunks per sequence

typedef __attribute__((ext_vector_type(8))) short short8;
typedef __attribute__((ext_vector_type(4))) float f32x4;

__device__ __forceinline__ float ds4t_softplus(float x) {
  return (x > 20.0f) ? x : log1pf(expf(x));
}

// ---- weights f32 -> bf16 (once) ----
__global__ void ds4t_wconv(const float* __restrict__ w, __hip_bfloat16* __restrict__ wb, int n) {
  int i = blockIdx.x * 256 + threadIdx.x;
  if (i < n) wb[i] = __float2bfloat16(w[i]);
}

// ---- encoder ----
__global__ void ds4t_encoder(const float* __restrict__ x, const float* __restrict__ ew,
                             const float* __restrict__ eb, float* __restrict__ H) {
  __shared__ float xrow[DIN];
  const int row = blockIdx.x;
  const int tid = threadIdx.x;
  if (tid < DIN) xrow[tid] = x[(size_t)row * DIN + tid];
  __syncthreads();
  for (int half = 0; half < 2; ++half) {
    const int j = tid + half * 256;
    float acc = eb[j];
#pragma unroll
    for (int k = 0; k < DIN; ++k) acc = fmaf(xrow[k], ew[(size_t)k * HH + j], acc);
    H[(size_t)row * HH + j] = acc;
  }
}

// ---- scan pass 1 (mode-parallel): thread = (hl, mg); 4 modes/thread; write end-states ----
__global__ __launch_bounds__(256) void ds4t_ssm_p1(
    const float* __restrict__ Hin, float* __restrict__ E,
    const float* __restrict__ log_dt, const float* __restrict__ logAre,
    const float* __restrict__ Aimag) {
  const int blk = blockIdx.x;
  const int hblk = blk & 15;                 // 16 h-blocks of 32
  const int c = (blk >> 4) & (NC - 1);
  const int b = blk >> 9;
  const int tid = threadIdx.x;
  const int mg = tid & 7;
  const int hl = tid >> 3;
  const int h = hblk * 32 + hl;

  const float dt = expf(log_dt[h]);
  float wre[4], wim[4], sre[4], sim[4];
#pragma unroll
  for (int j = 0; j < 4; ++j) {
    const int n = mg * 4 + j;
    const size_t p = (size_t)h * NN + n;
    const float Are = -expf(logAre[p]);
    const float Aim = Aimag[p];
    const float mag = expf(Are * dt);
    wre[j] = mag * cosf(Aim * dt);
    wim[j] = mag * sinf(Aim * dt);
    sre[j] = 0.0f; sim[j] = 0.0f;
  }

  const float* uptr = Hin + ((size_t)b * LL + (size_t)c * CT) * HH + h;
  float unext = uptr[0];
  for (int i = 0; i < CT; ++i) {
    const float u = unext;
    if (i + 1 < CT) unext = uptr[(size_t)(i + 1) * HH];
#pragma unroll
    for (int j = 0; j < 4; ++j) {
      const float nr = fmaf(wre[j], sre[j], fmaf(-wim[j], sim[j], u));
      const float ni = fmaf(wim[j], sre[j], wre[j] * sim[j]);
      sre[j] = nr; sim[j] = ni;
    }
  }
  float* ep = E + (((size_t)(b * 512 + h) * NC + c) * NN + (size_t)mg * 4) * 2;
#pragma unroll
  for (int j = 0; j < 4; ++j) { ep[2 * j] = sre[j]; ep[2 * j + 1] = sim[j]; }
}

// ---- scan combine: exclusive prefix over chunks ----
__global__ void ds4t_ssm_comb(float* __restrict__ E, const float* __restrict__ log_dt,
                              const float* __restrict__ logAre, const float* __restrict__ Aimag) {
  const int gid = blockIdx.x * 256 + threadIdx.x;   // bh*32 + n
  const int n = gid & 31;
  const int bh = gid >> 5;
  const int h = bh & 511;
  const float dt = expf(log_dt[h]);
  const size_t p = (size_t)h * NN + n;
  const float Are = -expf(logAre[p]);
  const float Aim = Aimag[p];
  const float magT = expf((float)CT * Are * dt);
  const float angT = (float)CT * Aim * dt;
  const float wTr = magT * cosf(angT);
  const float wTi = magT * sinf(angT);
  float* ep = E + ((size_t)bh * NC * NN + n) * 2;
  float Sr = 0.0f, Si = 0.0f;
  for (int c = 0; c < NC; ++c) {
    const float Er = ep[(size_t)c * NN * 2];
    const float Ei = ep[(size_t)c * NN * 2 + 1];
    ep[(size_t)c * NN * 2] = Sr;
    ep[(size_t)c * NN * 2 + 1] = Si;
    const float nSr = fmaf(wTr, Sr, fmaf(-wTi, Si, Er));
    const float nSi = fmaf(wTi, Sr, fmaf(wTr, Si, Ei));
    Sr = nSr; Si = nSi;
  }
}

// ---- scan pass 2 (mode-parallel): seeded scan + shfl reduce + D skip + gelu -> Y bf16 ----
__global__ __launch_bounds__(256) void ds4t_ssm_p2(
    const float* __restrict__ Hin, __hip_bfloat16* __restrict__ Y, const float* __restrict__ E,
    const float* __restrict__ log_dt, const float* __restrict__ Cpk,
    const float* __restrict__ logAre, const float* __restrict__ Aimag,
    const float* __restrict__ Dvec) {
  const int blk = blockIdx.x;
  const int hblk = blk & 15;
  const int c = (blk >> 4) & (NC - 1);
  const int b = blk >> 9;
  const int tid = threadIdx.x;
  const int mg = tid & 7;
  const int hl = tid >> 3;
  const int h = hblk * 32 + hl;

  const float dt = expf(log_dt[h]);
  const float Dh = Dvec[h];

  float wre[4], wim[4], cre[4], cim[4], sre[4], sim[4];
  const float* ep = E + (((size_t)(b * 512 + h) * NC + c) * NN + (size_t)mg * 4) * 2;
#pragma unroll
  for (int j = 0; j < 4; ++j) {
    const int n = mg * 4 + j;
    const size_t p = (size_t)h * NN + n;
    const float Are = -expf(logAre[p]);
    const float Aim = Aimag[p];
    const float mag = expf(Are * dt);
    const float cwr = mag * cosf(Aim * dt);
    const float cwi = mag * sinf(Aim * dt);
    wre[j] = cwr; wim[j] = cwi;
    const float inv = 1.0f / (Are * Are + Aim * Aim);
    const float qr = ((cwr - 1.0f) * Are + cwi * Aim) * inv;
    const float qi = (cwi * Are - (cwr - 1.0f) * Aim) * inv;
    const float Cr = Cpk[p * 2], Ci = Cpk[p * 2 + 1];
    cre[j] = Cr * qr - Ci * qi;
    cim[j] = Cr * qi + Ci * qr;
    sre[j] = ep[2 * j];
    sim[j] = ep[2 * j + 1];
  }

  const float* uptr = Hin + ((size_t)b * LL + (size_t)c * CT) * HH + h;
  __hip_bfloat16* yptr = Y + ((size_t)b * LL + (size_t)c * CT) * HH + h;

  float unext = uptr[0];
  for (int i = 0; i < CT; ++i) {
    const float u = unext;
    if (i + 1 < CT) unext = uptr[(size_t)(i + 1) * HH];
    float pp = 0.0f;
#pragma unroll
    for (int j = 0; j < 4; ++j) {
      const float nr = fmaf(wre[j], sre[j], fmaf(-wim[j], sim[j], u));
      const float ni = fmaf(wim[j], sre[j], wre[j] * sim[j]);
      sre[j] = nr; sim[j] = ni;
      pp = fmaf(cre[j], nr, fmaf(-cim[j], ni, pp));
    }
    pp += __shfl_xor(pp, 1);
    pp += __shfl_xor(pp, 2);
    pp += __shfl_xor(pp, 4);
    if (mg == 0) {
      const float yv = fmaf(2.0f, pp, Dh * u);
      const float gl = 0.5f * yv * (1.0f + erff(yv * 0.70710678118654752f));
      yptr[(size_t)i * HH] = __float2bfloat16(gl);
    }
  }
}

// ---- MFMA bf16 GEMM + bias + GLU -> Z f32 ----
__global__ __launch_bounds__(256) void ds4t_mlp(
    const __hip_bfloat16* __restrict__ A, const __hip_bfloat16* __restrict__ W,
    const float* __restrict__ bias, float* __restrict__ Z) {
  __shared__ __align__(16) unsigned short sA[128 * 32];
  __shared__ __align__(16) unsigned short sW0[128 * 32];
  __shared__ __align__(16) unsigned short sW1[128 * 32];

  const int tid = threadIdx.x;
  const int m0 = blockIdx.x * 128;
  const int o0 = blockIdx.y * 128;
  const int lane = tid & 63, wid = tid >> 6;
  const int mw = (wid >> 1) * 64, nw = (wid & 1) * 64;
  const int l15 = lane & 15, ko = lane >> 4;

  const unsigned short* Aus = (const unsigned short*)A;
  const unsigned short* Wus = (const unsigned short*)W;

  f32x4 acc[2][4][4] = {};

  for (int kt = 0; kt < 16; ++kt) {
#pragma unroll
    for (int r = 0; r < 2; ++r) {
      const int cidx = tid + r * 256;
      const int row = cidx >> 2, kb = cidx & 3;
      const int ldso = row * 32 + kb * 8;
      const int gk = kt * 32 + kb * 8;
      *(uint4*)&sA[ldso]  = *(const uint4*)&Aus[(size_t)(m0 + row) * HH + gk];
      *(uint4*)&sW0[ldso] = *(const uint4*)&Wus[(size_t)(o0 + row) * HH + gk];
      *(uint4*)&sW1[ldso] = *(const uint4*)&Wus[(size_t)(o0 + 512 + row) * HH + gk];
    }
    __syncthreads();

    short8 af[4], wf0[4], wf1[4];
#pragma unroll
    for (int mi = 0; mi < 4; ++mi)
      af[mi] = *(const short8*)&sA[(mw + mi * 16 + l15) * 32 + ko * 8];
#pragma unroll
    for (int ni = 0; ni < 4; ++ni) {
      wf0[ni] = *(const short8*)&sW0[(nw + ni * 16 + l15) * 32 + ko * 8];
      wf1[ni] = *(const short8*)&sW1[(nw + ni * 16 + l15) * 32 + ko * 8];
    }
#pragma unroll
    for (int mi = 0; mi < 4; ++mi)
#pragma unroll
      for (int ni = 0; ni < 4; ++ni) {
        acc[0][mi][ni] = __builtin_amdgcn_mfma_f32_16x16x32_bf16(af[mi], wf0[ni], acc[0][mi][ni], 0, 0, 0);
        acc[1][mi][ni] = __builtin_amdgcn_mfma_f32_16x16x32_bf16(af[mi], wf1[ni], acc[1][mi][ni], 0, 0, 0);
      }
    __syncthreads();
  }

#pragma unroll
  for (int mi = 0; mi < 4; ++mi)
#pragma unroll
    for (int ni = 0; ni < 4; ++ni)
#pragma unroll
      for (int r = 0; r < 4; ++r) {
        const int m = m0 + mw + mi * 16 + ko * 4 + r;
        const int oc = nw + ni * 16 + l15;
        const float a = acc[0][mi][ni][r] + bias[o0 + oc];
        const float g = acc[1][mi][ni][r] + bias[o0 + 512 + oc];
        Z[(size_t)m * HH + o0 + oc] = a / (1.0f + expf(-g));
      }
}

// ---- residual + LayerNorm (postnorm) ----
__global__ void ds4t_postnorm(const float* __restrict__ Z, float* __restrict__ H,
                              const float* __restrict__ gw, const float* __restrict__ gb) {
  __shared__ float red1[256];
  __shared__ float red2[256];
  const int row = blockIdx.x;
  const int tid = threadIdx.x;
  const float* zp = Z + (size_t)row * HH;
  float* hp = H + (size_t)row * HH;
  const float a0 = zp[tid] + hp[tid];
  const float a1 = zp[tid + 256] + hp[tid + 256];
  red1[tid] = a0 + a1;
  red2[tid] = fmaf(a0, a0, a1 * a1);
  __syncthreads();
  for (int off = 128; off > 0; off >>= 1) {
    if (tid < off) { red1[tid] += red1[tid + off]; red2[tid] += red2[tid + off]; }
    __syncthreads();
  }
  const float mean = red1[0] * (1.0f / HH);
  const float var = red2[0] * (1.0f / HH) - mean * mean;
  const float rstd = rsqrtf(var + 1e-5f);
  hp[tid] = (a0 - mean) * rstd * gw[tid] + gb[tid];
  hp[tid + 256] = (a1 - mean) * rstd * gw[tid + 256] + gb[tid + 256];
}

// ---- heads ----
__global__ void ds4t_project(const float* __restrict__ H, const float* __restrict__ mw,
                             const float* __restrict__ mb, const float* __restrict__ aw,
                             const float* __restrict__ ab,
                             float* __restrict__ mu_out, float* __restrict__ al_out) {
  __shared__ float red1[256];
  __shared__ float red2[256];
  const int row = blockIdx.x;
  const int tid = threadIdx.x;
  const float* hp = H + (size_t)row * HH;
  const float v0 = hp[tid], v1 = hp[tid + 256];
  red1[tid] = fmaf(v0, mw[tid], v1 * mw[tid + 256]);
  red2[tid] = fmaf(v0, aw[tid], v1 * aw[tid + 256]);
  __syncthreads();
  for (int off = 128; off > 0; off >>= 1) {
    if (tid < off) { red1[tid] += red1[tid + off]; red2[tid] += red2[tid + off]; }
    __syncthreads();
  }
  if (tid == 0) {
    mu_out[row] = ds4t_softplus(red1[0] + mb[0]);
    al_out[row] = ds4t_softplus(red2[0] + ab[0]);
  }
}

extern "C" void kernel_launch(void* const* d_in, const int* in_sizes, int n_in,
                              void* d_out, int out_size, void* d_ws, size_t ws_size,
                              hipStream_t stream) {
  const float* x      = (const float*)d_in[0];
  const float* enc_w  = (const float*)d_in[1];
  const float* enc_b  = (const float*)d_in[2];
  const float* log_dt = (const float*)d_in[3];
  const float* Cpk    = (const float*)d_in[4];
  const float* logAre = (const float*)d_in[5];
  const float* Aimag  = (const float*)d_in[6];
  const float* Dvec   = (const float*)d_in[7];
  const float* out_w  = (const float*)d_in[8];
  const float* out_b  = (const float*)d_in[9];
  const float* norm_w = (const float*)d_in[10];
  const float* norm_b = (const float*)d_in[11];
  const float* mu_w   = (const float*)d_in[12];
  const float* mu_b   = (const float*)d_in[13];
  const float* al_w   = (const float*)d_in[14];
  const float* al_b   = (const float*)d_in[15];

  const size_t WB = (size_t)NLAYER * 1024 * 512 * 2;
  const size_t seqH = (size_t)LL * HH * 4;
  const size_t seqY = (size_t)LL * HH * 2;
  const size_t seqE = (size_t)512 * NC * NN * 2 * 4;
  int Bc = BB;
  while (Bc > 1 && WB + (2 * seqH + seqY + seqE) * (size_t)Bc > ws_size) Bc >>= 1;

  char* ws = (char*)d_ws;
  __hip_bfloat16* Wbf = (__hip_bfloat16*)ws;
  float* Hbuf = (float*)(ws + WB);
  float* Zbuf = Hbuf + (size_t)Bc * LL * HH;
  __hip_bfloat16* Ybf = (__hip_bfloat16*)(Zbuf + (size_t)Bc * LL * HH);
  float* Ebuf = (float*)((char*)Ybf + (size_t)Bc * seqY);

  float* mu_out = (float*)d_out;
  float* al_out = mu_out + (size_t)ML;

  ds4t_wconv<<<(NLAYER * 1024 * 512 + 255) / 256, 256, 0, stream>>>(
      out_w, Wbf, NLAYER * 1024 * 512);

  for (int cb = 0; cb < BB; cb += Bc) {
    const int rows = Bc * LL;
    ds4t_encoder<<<rows, 256, 0, stream>>>(x + (size_t)cb * LL * DIN, enc_w, enc_b, Hbuf);

    for (int layer = 0; layer < NLAYER; ++layer) {
      const float* ldt = log_dt + (size_t)layer * HH;
      const float* lar = logAre + (size_t)layer * HH * NN;
      const float* aim = Aimag + (size_t)layer * HH * NN;

      ds4t_ssm_p1<<<Bc * NC * 16, 256, 0, stream>>>(Hbuf, Ebuf, ldt, lar, aim);
      ds4t_ssm_comb<<<(Bc * 512 * 32) / 256, 256, 0, stream>>>(Ebuf, ldt, lar, aim);
      ds4t_ssm_p2<<<Bc * NC * 16, 256, 0, stream>>>(
          Hbuf, Ybf, Ebuf, ldt, Cpk + (size_t)layer * HH * NN * 2, lar, aim,
          Dvec + (size_t)layer * HH);

      dim3 grid(rows / 128, 4, 1);
      ds4t_mlp<<<grid, 256, 0, stream>>>(
          Ybf, Wbf + (size_t)layer * 1024 * 512, out_b + (size_t)layer * 1024, Zbuf);
      ds4t_postnorm<<<rows, 256, 0, stream>>>(
          Zbuf, Hbuf, norm_w + (size_t)layer * HH, norm_b + (size_t)layer * HH);
    }

    ds4t_project<<<rows, 256, 0, stream>>>(
        Hbuf, mu_w, mu_b, al_w, al_b,
        mu_out + (size_t)cb * LL, al_out + (size_t)cb * LL);
  }
}